// Round 7
// baseline (619.243 us; speedup 1.0000x reference)
//
#include <hip/hip_runtime.h>
#include <math.h>

#define N_ROWS 1024
#define DIM    512
#define KQ     65536
#define KNN    200
#define NCLS   1000
#define NBINS  4096
#define CAP    2048
#define INV_T  14.285714285714286f  // 1/0.07

typedef unsigned short u16;
typedef __attribute__((ext_vector_type(8))) short short8;
typedef __attribute__((ext_vector_type(4))) float f32x4;
typedef __attribute__((ext_vector_type(2))) unsigned uint2v;
typedef __attribute__((ext_vector_type(4))) float float4v;
struct alignas(8) U16x4 { u16 x, y, z, w; };

#define GLOAD_LDS16(g, l)                                               \
    __builtin_amdgcn_global_load_lds(                                   \
        (__attribute__((address_space(1))) void*)(g),                   \
        (__attribute__((address_space(3))) void*)(l), 16, 0, 0)

// ---------------------------------------------------------------------------
// fp32 -> (hi, lo) bf16 split.  x = hi + lo + O(2^-18 x)
// ---------------------------------------------------------------------------
__device__ __forceinline__ void split1(float x, u16& h, u16& l) {
    unsigned u = __float_as_uint(x);
    unsigned hr = (u + 0x7FFFu + ((u >> 16) & 1u)) >> 16;  // RNE to bf16
    float hf = __uint_as_float(hr << 16);
    float lo = x - hf;
    unsigned ul = __float_as_uint(lo);
    unsigned lr = (ul + 0x7FFFu + ((ul >> 16) & 1u)) >> 16;
    h = (u16)hr; l = (u16)lr;
}

__device__ __forceinline__ void nt_store_u16x4(u16* p, U16x4 v) {
    uint2v w;
    w.x = (unsigned)v.x | ((unsigned)v.y << 16);
    w.y = (unsigned)v.z | ((unsigned)v.w << 16);
    __builtin_nontemporal_store(w, (uint2v*)p);
}

// ---------------------------------------------------------------------------
// Fused: queue circular update + bf16 plane split of B (=old qf) and A (=feats)
// All produced-for-later-kernels buffers stored NON-TEMPORAL (bypass local L2
// dirty state; consumers are on other XCDs -> avoid remote-dirty snoop path).
// ---------------------------------------------------------------------------
#define QF_BLOCKS (KQ * DIM / 4 / 256)        // 32768
#define FT_BLOCKS (N_ROWS * DIM / 4 / 256)    // 512

__global__ __launch_bounds__(256) void fused_update_split_kernel(
    const float* __restrict__ feats, const float* __restrict__ qf,
    const int* __restrict__ labels, const int* __restrict__ ql,
    const int* __restrict__ qptr,
    float* __restrict__ out_qf, float* __restrict__ out_ql,
    float* __restrict__ out_ptr,
    u16* __restrict__ Bhi, u16* __restrict__ Blo,
    u16* __restrict__ Ahi, u16* __restrict__ Alo) {
    int ptr = qptr[0];
    int b = blockIdx.x;
    if (b < QF_BLOCKS) {
        size_t t = (size_t)b * 256 + threadIdx.x;   // quad index into qf
        size_t idx = t * 4;
        int row = (int)(idx >> 9);
        int col = (int)(idx & 511);
        float4 v = *(const float4*)(qf + idx);
        U16x4 h, l;
        split1(v.x, h.x, l.x); split1(v.y, h.y, l.y);
        split1(v.z, h.z, l.z); split1(v.w, h.w, l.w);
        nt_store_u16x4(Bhi + idx, h);
        nt_store_u16x4(Blo + idx, l);
        int d = row - ptr; if (d < 0) d += KQ;
        float4 o = (d < N_ROWS) ? *(const float4*)(feats + (size_t)d * DIM + col) : v;
        float4v ov; ov.x = o.x; ov.y = o.y; ov.z = o.z; ov.w = o.w;
        __builtin_nontemporal_store(ov, (float4v*)(out_qf + idx));
        if (col == 0)
            out_ql[row] = (float)((d < N_ROWS) ? labels[d] : ql[row]);
    } else {
        size_t t = (size_t)(b - QF_BLOCKS) * 256 + threadIdx.x;  // quad in feats
        size_t idx = t * 4;
        float4 v = *(const float4*)(feats + idx);
        U16x4 h, l;
        split1(v.x, h.x, l.x); split1(v.y, h.y, l.y);
        split1(v.z, h.z, l.z); split1(v.w, h.w, l.w);
        nt_store_u16x4(Ahi + idx, h);
        nt_store_u16x4(Alo + idx, l);
        if (t == 0) out_ptr[0] = (float)((ptr + N_ROWS) % KQ);
    }
}

// ===========================================================================
// 256x256 8-wave BK=64 double-buffered phase-scheduled split-bf16 GEMM.
// C = Ahi.Bhi + Ahi.Blo + Alo.Bhi via K-concat: K_eff = 1536, 24 K-tiles.
// C stored NON-TEMPORAL (consumed by topk on other XCDs).
// ===========================================================================
#define NKT 24

#define STAGE8(kt_, dA, dB)                                                    \
  {                                                                            \
    const u16* Ap_ = ((kt_) < 16) ? Ahi : Alo;                                 \
    const u16* Bp_ = (((kt_) >> 3) == 1) ? Blo : Bhi;                          \
    int ke_ = ((kt_) & 7) << 6;                                                \
    const u16* ga_ = Ap_ + (size_t)(r0A + srow) * DIM + ke_ + scol;            \
    const u16* gb_ = Bp_ + (size_t)(r0B + srow) * DIM + ke_ + scol;            \
    GLOAD_LDS16(ga_ + (size_t)(8 * w0) * DIM,         &dA[0][w0 * 512]);       \
    GLOAD_LDS16(ga_ + (size_t)(8 * w1) * DIM,         &dA[0][w1 * 512]);       \
    GLOAD_LDS16(ga_ + (size_t)(128 + 8 * w0) * DIM,   &dA[1][w0 * 512]);       \
    GLOAD_LDS16(ga_ + (size_t)(128 + 8 * w1) * DIM,   &dA[1][w1 * 512]);       \
    GLOAD_LDS16(gb_ + (size_t)(8 * w0) * DIM,         &dB[0][w0 * 512]);       \
    GLOAD_LDS16(gb_ + (size_t)(8 * w1) * DIM,         &dB[0][w1 * 512]);       \
    GLOAD_LDS16(gb_ + (size_t)(128 + 8 * w0) * DIM,   &dB[1][w0 * 512]);       \
    GLOAD_LDS16(gb_ + (size_t)(128 + 8 * w1) * DIM,   &dB[1][w1 * 512]);       \
  }

#define MM(t_, u_)                                                             \
  acc[t_][u_] = __builtin_amdgcn_mfma_f32_16x16x32_bf16(                       \
      fa[(t_) & 3][0], fb[u_][0], acc[t_][u_], 0, 0, 0);                       \
  acc[t_][u_] = __builtin_amdgcn_mfma_f32_16x16x32_bf16(                       \
      fa[(t_) & 3][1], fb[u_][1], acc[t_][u_], 0, 0, 0);

#define TILE(kt_, RA, RB, SA, SB, DO_STAGE)                                    \
  {                                                                            \
    asm volatile("s_waitcnt vmcnt(0)" ::: "memory");                           \
    __builtin_amdgcn_s_barrier();                                              \
    const u16* aH_ = &RA[wm][0];                                               \
    const u16* bH_ = &RB[wn >> 1][bB];                                         \
    /* phase 0 */                                                              \
    _Pragma("unroll") for (int t = 0; t < 4; ++t) {                            \
      fa[t][0] = *(const short8*)(aH_ + t * 1024 + aoff + c0);                 \
      fa[t][1] = *(const short8*)(aH_ + t * 1024 + aoff + c1);                 \
    }                                                                          \
    _Pragma("unroll") for (int u = 0; u < 2; ++u) {                            \
      fb[u][0] = *(const short8*)(bH_ + u * 1024 + aoff + c0);                 \
      fb[u][1] = *(const short8*)(bH_ + u * 1024 + aoff + c1);                 \
    }                                                                          \
    if (DO_STAGE) STAGE8((kt_) + 1, SA, SB);                                   \
    __builtin_amdgcn_s_barrier();                                              \
    __builtin_amdgcn_s_setprio(1);                                             \
    _Pragma("unroll") for (int t = 0; t < 4; ++t) {                            \
      MM(t, 0); MM(t, 1);                                                      \
    }                                                                          \
    __builtin_amdgcn_s_setprio(0);                                             \
    __builtin_amdgcn_s_barrier();                                              \
    /* phase 1 */                                                              \
    _Pragma("unroll") for (int u = 2; u < 4; ++u) {                            \
      fb[u][0] = *(const short8*)(bH_ + u * 1024 + aoff + c0);                 \
      fb[u][1] = *(const short8*)(bH_ + u * 1024 + aoff + c1);                 \
    }                                                                          \
    __builtin_amdgcn_s_barrier();                                              \
    __builtin_amdgcn_s_setprio(1);                                             \
    _Pragma("unroll") for (int t = 0; t < 4; ++t) {                            \
      MM(t, 2); MM(t, 3);                                                      \
    }                                                                          \
    __builtin_amdgcn_s_setprio(0);                                             \
    __builtin_amdgcn_s_barrier();                                              \
    /* phase 2 */                                                              \
    _Pragma("unroll") for (int t = 0; t < 4; ++t) {                            \
      fa[t][0] = *(const short8*)(aH_ + (t + 4) * 1024 + aoff + c0);           \
      fa[t][1] = *(const short8*)(aH_ + (t + 4) * 1024 + aoff + c1);           \
    }                                                                          \
    __builtin_amdgcn_s_barrier();                                              \
    __builtin_amdgcn_s_setprio(1);                                             \
    _Pragma("unroll") for (int t = 4; t < 8; ++t) {                            \
      MM(t, 2); MM(t, 3);                                                      \
    }                                                                          \
    __builtin_amdgcn_s_setprio(0);                                             \
    __builtin_amdgcn_s_barrier();                                              \
    /* phase 3 */                                                              \
    __builtin_amdgcn_s_setprio(1);                                             \
    _Pragma("unroll") for (int t = 4; t < 8; ++t) {                            \
      MM(t, 0); MM(t, 1);                                                      \
    }                                                                          \
    __builtin_amdgcn_s_setprio(0);                                             \
  }

__global__ __launch_bounds__(512, 2) void gemm256_kernel(
    const u16* __restrict__ Ahi, const u16* __restrict__ Alo,
    const u16* __restrict__ Bhi, const u16* __restrict__ Blo,
    float* __restrict__ C) {
    __shared__ u16 sA0[2][8192], sB0[2][8192];
    __shared__ u16 sA1[2][8192], sB1[2][8192];

    int tid = threadIdx.x;
    int wv = tid >> 6, lane = tid & 63;
    int r = lane & 15, q = lane >> 4;
    int wm = wv >> 2, wn = wv & 3;          // 2 M-groups x 4 N-groups
    int srow = lane >> 3;                    // staging row-in-window
    int scol = ((lane & 7) ^ (lane >> 3)) << 3;   // pre-swizzled src col (elems)
    int w0 = wv, w1 = wv + 8;                // staging windows owned by wave
    int aoff = r << 6;                       // row*64 elems
    int c0 = (q << 3) ^ ((r & 7) << 3);      // kk=0 swizzled col (elems)
    int c1 = (32 | (q << 3)) ^ ((r & 7) << 3);   // kk=1
    int bB = (wn & 1) << 12;                 // B local-row base (elems)
    int r0A = blockIdx.y << 8;
    int r0B = blockIdx.x << 8;

    f32x4 acc[8][4] = {};
    short8 fa[4][2], fb[4][2];

    STAGE8(0, sA0, sB0);

    for (int kt = 0; kt < NKT; kt += 2) {
        TILE(kt,     sA0, sB0, sA1, sB1, 1);
        TILE(kt + 1, sA1, sB1, sA0, sB0, (kt + 2) < NKT);
    }

#pragma unroll
    for (int t = 0; t < 8; ++t)
#pragma unroll
        for (int u = 0; u < 4; ++u)
#pragma unroll
            for (int g = 0; g < 4; ++g) {
                int row = r0A + wm * 128 + t * 16 + q * 4 + g;
                int col = r0B + wn * 64 + u * 16 + r;
                __builtin_nontemporal_store(acc[t][u][g],
                                            &C[(size_t)row * KQ + col]);
            }
}

// ---------------------------------------------------------------------------
// 128x128 split-bf16 GEMM (fallback when CH=128)
// ---------------------------------------------------------------------------
__global__ __launch_bounds__(256, 4) void gemm_mfma_kernel(
    const u16* __restrict__ Ahi, const u16* __restrict__ Alo,
    const u16* __restrict__ Bhi, const u16* __restrict__ Blo,
    float* __restrict__ C) {
    __shared__ u16 sA[2][128 * 32];
    __shared__ u16 sB[2][128 * 32];

    int tid = threadIdx.x;
    int wave = tid >> 6, lane = tid & 63;
    int q = lane >> 4, r = lane & 15;
    int bn = blockIdx.x, bm = blockIdx.y;
    int wm = wave & 1, wn = wave >> 1;

    const u16* gplane = (wave == 0) ? Ahi : (wave == 1) ? Alo
                      : (wave == 2) ? Bhi : Blo;
    int prow0 = (wave < 2) ? bm * 128 : bn * 128;
    const u16* gbase = gplane + (size_t)prow0 * DIM;
    u16* lbase = (wave == 0) ? sA[0] : (wave == 1) ? sA[1]
               : (wave == 2) ? sB[0] : sB[1];
    int lrow = lane >> 2;
    int lchunk = lane & 3;

    f32x4 acc[4][4] = {};

    for (int kt = 0; kt < DIM; kt += 32) {
        __syncthreads();
#pragma unroll
        for (int s = 0; s < 8; ++s) {
            const u16* g = gbase + (size_t)(s * 16 + lrow) * DIM + kt + lchunk * 8;
            GLOAD_LDS16(g, lbase + s * 512);
        }
        __syncthreads();

        short8 fa[2][4], fb[2][4];
#pragma unroll
        for (int t = 0; t < 4; ++t) {
            int am = wm * 64 + t * 16 + r;
            fa[0][t] = *(const short8*)&sA[0][am * 32 + q * 8];
            fa[1][t] = *(const short8*)&sA[1][am * 32 + q * 8];
            int bn_ = wn * 64 + t * 16 + r;
            fb[0][t] = *(const short8*)&sB[0][bn_ * 32 + q * 8];
            fb[1][t] = *(const short8*)&sB[1][bn_ * 32 + q * 8];
        }
#pragma unroll
        for (int i = 0; i < 4; ++i)
#pragma unroll
            for (int j = 0; j < 4; ++j) {
                acc[i][j] = __builtin_amdgcn_mfma_f32_16x16x32_bf16(
                    fa[0][i], fb[0][j], acc[i][j], 0, 0, 0);
                acc[i][j] = __builtin_amdgcn_mfma_f32_16x16x32_bf16(
                    fa[0][i], fb[1][j], acc[i][j], 0, 0, 0);
                acc[i][j] = __builtin_amdgcn_mfma_f32_16x16x32_bf16(
                    fa[1][i], fb[0][j], acc[i][j], 0, 0, 0);
            }
    }

#pragma unroll
    for (int i = 0; i < 4; ++i)
#pragma unroll
        for (int j = 0; j < 4; ++j)
#pragma unroll
            for (int g = 0; g < 4; ++g) {
                int row = bm * 128 + wm * 64 + i * 16 + q * 4 + g;
                int col = bn * 128 + wn * 64 + j * 16 + r;
                C[(size_t)row * KQ + col] = acc[i][j][g];
            }
}

// ---------------------------------------------------------------------------
// fp32 fallback GEMM (only if ws too small for planes)
// ---------------------------------------------------------------------------
#define LSTR 68
#define LA(k, m) ((k) * LSTR + (m))

__global__ __launch_bounds__(256) void gemm_nt_kernel(
    const float* __restrict__ A, const float* __restrict__ B,
    float* __restrict__ C) {
    __shared__ float As[32 * LSTR];
    __shared__ float Bs[32 * LSTR];
    int tid = threadIdx.x;
    int bn = blockIdx.x, bm = blockIdx.y;
    int tx = tid & 15, ty = tid >> 4;
    int lm = tid >> 3;
    int lk = (tid & 7) * 4;
    const float* Ab = A + (size_t)bm * 64 * DIM;
    const float* Bb = B + (size_t)bn * 64 * DIM;
    float acc[4][4] = {};
    for (int kt = 0; kt < DIM; kt += 32) {
        float4 a0 = *(const float4*)(Ab + (size_t)lm * DIM + kt + lk);
        float4 a1 = *(const float4*)(Ab + (size_t)(lm + 32) * DIM + kt + lk);
        float4 b0 = *(const float4*)(Bb + (size_t)lm * DIM + kt + lk);
        float4 b1 = *(const float4*)(Bb + (size_t)(lm + 32) * DIM + kt + lk);
        __syncthreads();
        As[LA(lk + 0, lm)] = a0.x;  As[LA(lk + 1, lm)] = a0.y;
        As[LA(lk + 2, lm)] = a0.z;  As[LA(lk + 3, lm)] = a0.w;
        As[LA(lk + 0, lm + 32)] = a1.x;  As[LA(lk + 1, lm + 32)] = a1.y;
        As[LA(lk + 2, lm + 32)] = a1.z;  As[LA(lk + 3, lm + 32)] = a1.w;
        Bs[LA(lk + 0, lm)] = b0.x;  Bs[LA(lk + 1, lm)] = b0.y;
        Bs[LA(lk + 2, lm)] = b0.z;  Bs[LA(lk + 3, lm)] = b0.w;
        Bs[LA(lk + 0, lm + 32)] = b1.x;  Bs[LA(lk + 1, lm + 32)] = b1.y;
        Bs[LA(lk + 2, lm + 32)] = b1.z;  Bs[LA(lk + 3, lm + 32)] = b1.w;
        __syncthreads();
#pragma unroll
        for (int kk = 0; kk < 32; ++kk) {
            float4 av = *(const float4*)&As[LA(kk, ty * 4)];
            float4 bv = *(const float4*)&Bs[LA(kk, tx * 4)];
            float a_[4] = {av.x, av.y, av.z, av.w};
            float b_[4] = {bv.x, bv.y, bv.z, bv.w};
#pragma unroll
            for (int i = 0; i < 4; ++i)
#pragma unroll
                for (int j = 0; j < 4; ++j) acc[i][j] += a_[i] * b_[j];
        }
    }
    for (int i = 0; i < 4; ++i) {
        float4 o = make_float4(acc[i][0], acc[i][1], acc[i][2], acc[i][3]);
        *(float4*)(C + (size_t)(bm * 64 + ty * 4 + i) * KQ + bn * 64 + tx * 4) = o;
    }
}

// ---------------------------------------------------------------------------
// Per-row top-200: radix histogram + exact rank + vote + argmax.
// (round-3 version: 1024 threads, wave-shuffle scan/argmax)
// ---------------------------------------------------------------------------
__device__ __forceinline__ unsigned order_key(float v) {
    unsigned u = __float_as_uint(v);
    return u ^ ((u & 0x80000000u) ? 0xFFFFFFFFu : 0x80000000u);
}

__global__ __launch_bounds__(1024) void topk_kernel(
    const float* __restrict__ sim, int r0,
    const int* __restrict__ ql, const int* __restrict__ labels,
    float* __restrict__ flags) {
    __shared__ unsigned hist[NBINS];
    __shared__ float cval[CAP];
    __shared__ int   cidx[CAP];
    __shared__ float scores[NCLS];
    __shared__ unsigned wsum[16];
    __shared__ float rb[16];
    __shared__ int   rc[16];
    __shared__ int s_bstar, s_ncand;

    int row = blockIdx.x;
    int tid = threadIdx.x;
    int lane = tid & 63;
    int wv = tid >> 6;
    const float4* s4 = (const float4*)(sim + (size_t)row * KQ);

    hist[tid] = 0; hist[tid + 1024] = 0; hist[tid + 2048] = 0; hist[tid + 3072] = 0;
    if (tid == 0) s_ncand = 0;
    __syncthreads();

    // pass 1: 12-bit histogram
    for (int i4 = tid; i4 < KQ / 4; i4 += 1024) {
        float4 v = s4[i4];
        atomicAdd(&hist[order_key(v.x) >> 20], 1u);
        atomicAdd(&hist[order_key(v.y) >> 20], 1u);
        atomicAdd(&hist[order_key(v.z) >> 20], 1u);
        atomicAdd(&hist[order_key(v.w) >> 20], 1u);
    }
    __syncthreads();

    // suffix scan: thread t owns bins [4t, 4t+4). Wave shfl suffix + cross-wave.
    unsigned loc = hist[4 * tid] + hist[4 * tid + 1] +
                   hist[4 * tid + 2] + hist[4 * tid + 3];
    unsigned x = loc;
#pragma unroll
    for (int off = 1; off < 64; off <<= 1) {
        unsigned y = __shfl_down(x, off);
        if (lane + off < 64) x += y;
    }
    if (lane == 0) wsum[wv] = x;
    __syncthreads();
    unsigned above = 0;
#pragma unroll
    for (int w2 = 0; w2 < 16; ++w2)
        if (w2 > wv) above += wsum[w2];
    unsigned running = above + x - loc;   // count in bins above this thread's chunk
    for (int j = 3; j >= 0; --j) {
        unsigned c = hist[4 * tid + j];
        if (running < KNN && running + c >= KNN) s_bstar = 4 * tid + j;
        running += c;
    }
    __syncthreads();
    int bstar = s_bstar;

    // pass 2: collect candidates with bin >= b*
    for (int i4 = tid; i4 < KQ / 4; i4 += 1024) {
        float4 v = s4[i4];
        float vv[4] = {v.x, v.y, v.z, v.w};
#pragma unroll
        for (int c = 0; c < 4; ++c) {
            if ((int)(order_key(vv[c]) >> 20) >= bstar) {
                int p = atomicAdd(&s_ncand, 1);
                if (p < CAP) { cval[p] = vv[c]; cidx[p] = i4 * 4 + c; }
            }
        }
    }
    if (tid < NCLS) scores[tid] = 0.f;
    __syncthreads();

    // exact rank among candidates; vote
    int M = s_ncand; if (M > CAP) M = CAP;
    for (int c = tid; c < M; c += 1024) {
        float v = cval[c]; int id = cidx[c];
        int rank = 0;
        for (int j = 0; j < M; ++j) {
            float vj = cval[j];
            if (vj > v || (vj == v && cidx[j] < id)) rank++;
        }
        if (rank < KNN) {
            float w = expf(v * INV_T);
            atomicAdd(&scores[ql[id]], w);
        }
    }
    __syncthreads();

    // argmax over classes (ties -> lowest class) via wave shuffles
    float b2 = (tid < NCLS) ? scores[tid] : -1.f;
    int   c2 = (tid < NCLS) ? tid : 0x3FFFFFFF;
#pragma unroll
    for (int off = 1; off < 64; off <<= 1) {
        float ob = __shfl_down(b2, off);
        int   oc = __shfl_down(c2, off);
        if (lane + off < 64 && (ob > b2 || (ob == b2 && oc < c2))) { b2 = ob; c2 = oc; }
    }
    if (lane == 0) { rb[wv] = b2; rc[wv] = c2; }
    __syncthreads();
    if (tid < 64) {
        float b3 = -1.f; int c3 = 0x3FFFFFFF;
        if (tid < 16) { b3 = rb[tid]; c3 = rc[tid]; }
#pragma unroll
        for (int off = 1; off < 16; off <<= 1) {
            float ob = __shfl_down(b3, off);
            int   oc = __shfl_down(c3, off);
            if (tid + off < 16 && (ob > b3 || (ob == b3 && oc < c3))) { b3 = ob; c3 = oc; }
        }
        if (tid == 0)
            flags[r0 + row] = (c3 == labels[r0 + row]) ? 1.0f : 0.0f;
    }
}

__global__ __launch_bounds__(256) void acc_kernel(
    const float* __restrict__ flags, float* __restrict__ out) {
    __shared__ float r[256];
    int tid = threadIdx.x;
    r[tid] = flags[tid] + flags[tid + 256] + flags[tid + 512] + flags[tid + 768];
    __syncthreads();
    for (int off = 128; off; off >>= 1) {
        if (tid < off) r[tid] += r[tid + off];
        __syncthreads();
    }
    if (tid == 0) out[0] = r[0] * (1.0f / 1024.0f);
}

// ---------------------------------------------------------------------------
extern "C" void kernel_launch(void* const* d_in, const int* in_sizes, int n_in,
                              void* d_out, int out_size, void* d_ws, size_t ws_size,
                              hipStream_t stream) {
    const float* feats  = (const float*)d_in[0];
    const float* qf     = (const float*)d_in[1];
    const int*   labels = (const int*)d_in[2];
    const int*   ql     = (const int*)d_in[3];
    const int*   qptr   = (const int*)d_in[4];

    float* out     = (float*)d_out;
    float* out_qf  = out + 1;
    float* out_ql  = out_qf + (size_t)KQ * DIM;
    float* out_ptr = out_ql + KQ;

    const size_t bplane = (size_t)KQ * DIM;
    const size_t aplane = (size_t)N_ROWS * DIM;

    int CH = 0;
    for (int c = 512; c >= 128; c >>= 1) {
        size_t need = 2 * bplane * 2 + 2 * aplane * 2 +
                      (size_t)c * KQ * 4 + N_ROWS * 4;
        if (need <= ws_size) { CH = c; break; }
    }

    if (CH > 0) {
        u16* Bhi = (u16*)d_ws;
        u16* Blo = Bhi + bplane;
        u16* Ahi = Blo + bplane;
        u16* Alo = Ahi + aplane;
        float* sim   = (float*)(Alo + aplane);
        float* flags = sim + (size_t)CH * KQ;

        fused_update_split_kernel<<<QF_BLOCKS + FT_BLOCKS, 256, 0, stream>>>(
            feats, qf, labels, ql, qptr, out_qf, out_ql, out_ptr,
            Bhi, Blo, Ahi, Alo);

        int nchunks = N_ROWS / CH;
        for (int c = 0; c < nchunks; ++c) {
            if (CH >= 256) {
                dim3 g(KQ / 256, CH / 256);
                gemm256_kernel<<<g, 512, 0, stream>>>(
                    Ahi + (size_t)c * CH * DIM, Alo + (size_t)c * CH * DIM,
                    Bhi, Blo, sim);
            } else {
                dim3 g(KQ / 128, CH / 128);
                gemm_mfma_kernel<<<g, 256, 0, stream>>>(
                    Ahi + (size_t)c * CH * DIM, Alo + (size_t)c * CH * DIM,
                    Bhi, Blo, sim);
            }
            topk_kernel<<<CH, 1024, 0, stream>>>(sim, c * CH, ql, labels, flags);
        }
        acc_kernel<<<1, 256, 0, stream>>>(flags, out);
    } else {
        // fp32 fallback path
        int CHf = 256;
        while (CHf > 64 &&
               ((size_t)CHf * KQ * sizeof(float) + N_ROWS * sizeof(float)) > ws_size)
            CHf >>= 1;
        float* sim   = (float*)d_ws;
        float* flags = (float*)((char*)d_ws + (size_t)CHf * KQ * sizeof(float));
        fused_update_split_kernel<<<QF_BLOCKS + FT_BLOCKS, 256, 0, stream>>>(
            feats, qf, labels, ql, qptr, out_qf, out_ql, out_ptr,
            (u16*)sim, (u16*)sim, (u16*)sim, (u16*)sim);
        int nchunks = N_ROWS / CHf;
        for (int c = 0; c < nchunks; ++c) {
            const float* A = feats + (size_t)c * CHf * DIM;
            dim3 g(KQ / 64, CHf / 64);
            gemm_nt_kernel<<<g, 256, 0, stream>>>(A, qf, sim);
            topk_kernel<<<CHf, 1024, 0, stream>>>(sim, c * CHf, ql, labels, flags);
        }
        acc_kernel<<<1, 256, 0, stream>>>(flags, out);
    }
}

// Round 8
// 577.994 us; speedup vs baseline: 1.0714x; 1.0714x over previous
//
#include <hip/hip_runtime.h>
#include <math.h>

#define N_ROWS 1024
#define DIM    512
#define KQ     65536
#define KNN    200
#define NCLS   1000
#define NBINS  4096
#define CAP    2048
#define INV_T  14.285714285714286f  // 1/0.07

typedef unsigned short u16;
typedef __attribute__((ext_vector_type(8))) short short8;
typedef __attribute__((ext_vector_type(4))) float f32x4;
struct alignas(8) U16x4 { u16 x, y, z, w; };

#define GLOAD_LDS16(g, l)                                               \
    __builtin_amdgcn_global_load_lds(                                   \
        (__attribute__((address_space(1))) void*)(g),                   \
        (__attribute__((address_space(3))) void*)(l), 16, 0, 0)

__device__ __forceinline__ unsigned order_key(float v) {
    unsigned u = __float_as_uint(v);
    return u ^ ((u & 0x80000000u) ? 0xFFFFFFFFu : 0x80000000u);
}

// ---------------------------------------------------------------------------
// fp32 -> (hi, lo) bf16 split.  x = hi + lo + O(2^-18 x)
// ---------------------------------------------------------------------------
__device__ __forceinline__ void split1(float x, u16& h, u16& l) {
    unsigned u = __float_as_uint(x);
    unsigned hr = (u + 0x7FFFu + ((u >> 16) & 1u)) >> 16;  // RNE to bf16
    float hf = __uint_as_float(hr << 16);
    float lo = x - hf;
    unsigned ul = __float_as_uint(lo);
    unsigned lr = (ul + 0x7FFFu + ((ul >> 16) & 1u)) >> 16;
    h = (u16)hr; l = (u16)lr;
}

// ---------------------------------------------------------------------------
// Fused: queue circular update + bf16 plane split of B (=old qf) and A (=feats)
// ---------------------------------------------------------------------------
#define QF_BLOCKS (KQ * DIM / 4 / 256)        // 32768
#define FT_BLOCKS (N_ROWS * DIM / 4 / 256)    // 512

__global__ __launch_bounds__(256) void fused_update_split_kernel(
    const float* __restrict__ feats, const float* __restrict__ qf,
    const int* __restrict__ labels, const int* __restrict__ ql,
    const int* __restrict__ qptr,
    float* __restrict__ out_qf, float* __restrict__ out_ql,
    float* __restrict__ out_ptr,
    u16* __restrict__ Bhi, u16* __restrict__ Blo,
    u16* __restrict__ Ahi, u16* __restrict__ Alo) {
    int ptr = qptr[0];
    int b = blockIdx.x;
    if (b < QF_BLOCKS) {
        size_t t = (size_t)b * 256 + threadIdx.x;   // quad index into qf
        size_t idx = t * 4;
        int row = (int)(idx >> 9);
        int col = (int)(idx & 511);
        float4 v = *(const float4*)(qf + idx);
        U16x4 h, l;
        split1(v.x, h.x, l.x); split1(v.y, h.y, l.y);
        split1(v.z, h.z, l.z); split1(v.w, h.w, l.w);
        *(U16x4*)(Bhi + idx) = h;
        *(U16x4*)(Blo + idx) = l;
        int d = row - ptr; if (d < 0) d += KQ;
        float4 o = (d < N_ROWS) ? *(const float4*)(feats + (size_t)d * DIM + col) : v;
        *(float4*)(out_qf + idx) = o;
        if (col == 0)
            out_ql[row] = (float)((d < N_ROWS) ? labels[d] : ql[row]);
    } else {
        size_t t = (size_t)(b - QF_BLOCKS) * 256 + threadIdx.x;  // quad in feats
        size_t idx = t * 4;
        float4 v = *(const float4*)(feats + idx);
        U16x4 h, l;
        split1(v.x, h.x, l.x); split1(v.y, h.y, l.y);
        split1(v.z, h.z, l.z); split1(v.w, h.w, l.w);
        *(U16x4*)(Ahi + idx) = h;
        *(U16x4*)(Alo + idx) = l;
        if (t == 0) out_ptr[0] = (float)((ptr + N_ROWS) % KQ);
    }
}

// ===========================================================================
// 256x256 8-wave BK=64 double-buffered phase-scheduled split-bf16 GEMM.
// C = Ahi.Bhi + Ahi.Blo + Alo.Bhi via K-concat: K_eff = 1536, 24 K-tiles.
// Epilogue also writes u16 key sidecar (order_key >> 16) for topk.
// ===========================================================================
#define NKT 24

#define STAGE8(kt_, dA, dB)                                                    \
  {                                                                            \
    const u16* Ap_ = ((kt_) < 16) ? Ahi : Alo;                                 \
    const u16* Bp_ = (((kt_) >> 3) == 1) ? Blo : Bhi;                          \
    int ke_ = ((kt_) & 7) << 6;                                                \
    const u16* ga_ = Ap_ + (size_t)(r0A + srow) * DIM + ke_ + scol;            \
    const u16* gb_ = Bp_ + (size_t)(r0B + srow) * DIM + ke_ + scol;            \
    GLOAD_LDS16(ga_ + (size_t)(8 * w0) * DIM,         &dA[0][w0 * 512]);       \
    GLOAD_LDS16(ga_ + (size_t)(8 * w1) * DIM,         &dA[0][w1 * 512]);       \
    GLOAD_LDS16(ga_ + (size_t)(128 + 8 * w0) * DIM,   &dA[1][w0 * 512]);       \
    GLOAD_LDS16(ga_ + (size_t)(128 + 8 * w1) * DIM,   &dA[1][w1 * 512]);       \
    GLOAD_LDS16(gb_ + (size_t)(8 * w0) * DIM,         &dB[0][w0 * 512]);       \
    GLOAD_LDS16(gb_ + (size_t)(8 * w1) * DIM,         &dB[0][w1 * 512]);       \
    GLOAD_LDS16(gb_ + (size_t)(128 + 8 * w0) * DIM,   &dB[1][w0 * 512]);       \
    GLOAD_LDS16(gb_ + (size_t)(128 + 8 * w1) * DIM,   &dB[1][w1 * 512]);       \
  }

#define MM(t_, u_)                                                             \
  acc[t_][u_] = __builtin_amdgcn_mfma_f32_16x16x32_bf16(                       \
      fa[(t_) & 3][0], fb[u_][0], acc[t_][u_], 0, 0, 0);                       \
  acc[t_][u_] = __builtin_amdgcn_mfma_f32_16x16x32_bf16(                       \
      fa[(t_) & 3][1], fb[u_][1], acc[t_][u_], 0, 0, 0);

#define TILE(kt_, RA, RB, SA, SB, DO_STAGE)                                    \
  {                                                                            \
    asm volatile("s_waitcnt vmcnt(0)" ::: "memory");                           \
    __builtin_amdgcn_s_barrier();                                              \
    const u16* aH_ = &RA[wm][0];                                               \
    const u16* bH_ = &RB[wn >> 1][bB];                                         \
    /* phase 0 */                                                              \
    _Pragma("unroll") for (int t = 0; t < 4; ++t) {                            \
      fa[t][0] = *(const short8*)(aH_ + t * 1024 + aoff + c0);                 \
      fa[t][1] = *(const short8*)(aH_ + t * 1024 + aoff + c1);                 \
    }                                                                          \
    _Pragma("unroll") for (int u = 0; u < 2; ++u) {                            \
      fb[u][0] = *(const short8*)(bH_ + u * 1024 + aoff + c0);                 \
      fb[u][1] = *(const short8*)(bH_ + u * 1024 + aoff + c1);                 \
    }                                                                          \
    if (DO_STAGE) STAGE8((kt_) + 1, SA, SB);                                   \
    __builtin_amdgcn_s_barrier();                                              \
    __builtin_amdgcn_s_setprio(1);                                             \
    _Pragma("unroll") for (int t = 0; t < 4; ++t) {                            \
      MM(t, 0); MM(t, 1);                                                      \
    }                                                                          \
    __builtin_amdgcn_s_setprio(0);                                             \
    __builtin_amdgcn_s_barrier();                                              \
    /* phase 1 */                                                              \
    _Pragma("unroll") for (int u = 2; u < 4; ++u) {                            \
      fb[u][0] = *(const short8*)(bH_ + u * 1024 + aoff + c0);                 \
      fb[u][1] = *(const short8*)(bH_ + u * 1024 + aoff + c1);                 \
    }                                                                          \
    __builtin_amdgcn_s_barrier();                                              \
    __builtin_amdgcn_s_setprio(1);                                             \
    _Pragma("unroll") for (int t = 0; t < 4; ++t) {                            \
      MM(t, 2); MM(t, 3);                                                      \
    }                                                                          \
    __builtin_amdgcn_s_setprio(0);                                             \
    __builtin_amdgcn_s_barrier();                                              \
    /* phase 2 */                                                              \
    _Pragma("unroll") for (int t = 0; t < 4; ++t) {                            \
      fa[t][0] = *(const short8*)(aH_ + (t + 4) * 1024 + aoff + c0);           \
      fa[t][1] = *(const short8*)(aH_ + (t + 4) * 1024 + aoff + c1);           \
    }                                                                          \
    __builtin_amdgcn_s_barrier();                                              \
    __builtin_amdgcn_s_setprio(1);                                             \
    _Pragma("unroll") for (int t = 4; t < 8; ++t) {                            \
      MM(t, 2); MM(t, 3);                                                      \
    }                                                                          \
    __builtin_amdgcn_s_setprio(0);                                             \
    __builtin_amdgcn_s_barrier();                                              \
    /* phase 3 */                                                              \
    __builtin_amdgcn_s_setprio(1);                                             \
    _Pragma("unroll") for (int t = 4; t < 8; ++t) {                            \
      MM(t, 0); MM(t, 1);                                                      \
    }                                                                          \
    __builtin_amdgcn_s_setprio(0);                                             \
  }

__global__ __launch_bounds__(512, 2) void gemm256_kernel(
    const u16* __restrict__ Ahi, const u16* __restrict__ Alo,
    const u16* __restrict__ Bhi, const u16* __restrict__ Blo,
    float* __restrict__ C, u16* __restrict__ Ck) {
    __shared__ u16 sA0[2][8192], sB0[2][8192];
    __shared__ u16 sA1[2][8192], sB1[2][8192];

    int tid = threadIdx.x;
    int wv = tid >> 6, lane = tid & 63;
    int r = lane & 15, q = lane >> 4;
    int wm = wv >> 2, wn = wv & 3;          // 2 M-groups x 4 N-groups
    int srow = lane >> 3;                    // staging row-in-window
    int scol = ((lane & 7) ^ (lane >> 3)) << 3;   // pre-swizzled src col (elems)
    int w0 = wv, w1 = wv + 8;                // staging windows owned by wave
    int aoff = r << 6;                       // row*64 elems
    int c0 = (q << 3) ^ ((r & 7) << 3);      // kk=0 swizzled col (elems)
    int c1 = (32 | (q << 3)) ^ ((r & 7) << 3);   // kk=1
    int bB = (wn & 1) << 12;                 // B local-row base (elems)
    int r0A = blockIdx.y << 8;
    int r0B = blockIdx.x << 8;

    f32x4 acc[8][4] = {};
    short8 fa[4][2], fb[4][2];

    STAGE8(0, sA0, sB0);

    for (int kt = 0; kt < NKT; kt += 2) {
        TILE(kt,     sA0, sB0, sA1, sB1, 1);
        TILE(kt + 1, sA1, sB1, sA0, sB0, (kt + 2) < NKT);
    }

#pragma unroll
    for (int t = 0; t < 8; ++t)
#pragma unroll
        for (int u = 0; u < 4; ++u)
#pragma unroll
            for (int g = 0; g < 4; ++g) {
                int row = r0A + wm * 128 + t * 16 + q * 4 + g;
                int col = r0B + wn * 64 + u * 16 + r;
                float v = acc[t][u][g];
                size_t off = (size_t)row * KQ + col;
                C[off] = v;
                Ck[off] = (u16)(order_key(v) >> 16);
            }
}

// ---------------------------------------------------------------------------
// 128x128 split-bf16 GEMM (fallback when CH=128)
// ---------------------------------------------------------------------------
__global__ __launch_bounds__(256, 4) void gemm_mfma_kernel(
    const u16* __restrict__ Ahi, const u16* __restrict__ Alo,
    const u16* __restrict__ Bhi, const u16* __restrict__ Blo,
    float* __restrict__ C, u16* __restrict__ Ck) {
    __shared__ u16 sA[2][128 * 32];
    __shared__ u16 sB[2][128 * 32];

    int tid = threadIdx.x;
    int wave = tid >> 6, lane = tid & 63;
    int q = lane >> 4, r = lane & 15;
    int bn = blockIdx.x, bm = blockIdx.y;
    int wm = wave & 1, wn = wave >> 1;

    const u16* gplane = (wave == 0) ? Ahi : (wave == 1) ? Alo
                      : (wave == 2) ? Bhi : Blo;
    int prow0 = (wave < 2) ? bm * 128 : bn * 128;
    const u16* gbase = gplane + (size_t)prow0 * DIM;
    u16* lbase = (wave == 0) ? sA[0] : (wave == 1) ? sA[1]
               : (wave == 2) ? sB[0] : sB[1];
    int lrow = lane >> 2;
    int lchunk = lane & 3;

    f32x4 acc[4][4] = {};

    for (int kt = 0; kt < DIM; kt += 32) {
        __syncthreads();
#pragma unroll
        for (int s = 0; s < 8; ++s) {
            const u16* g = gbase + (size_t)(s * 16 + lrow) * DIM + kt + lchunk * 8;
            GLOAD_LDS16(g, lbase + s * 512);
        }
        __syncthreads();

        short8 fa[2][4], fb[2][4];
#pragma unroll
        for (int t = 0; t < 4; ++t) {
            int am = wm * 64 + t * 16 + r;
            fa[0][t] = *(const short8*)&sA[0][am * 32 + q * 8];
            fa[1][t] = *(const short8*)&sA[1][am * 32 + q * 8];
            int bn_ = wn * 64 + t * 16 + r;
            fb[0][t] = *(const short8*)&sB[0][bn_ * 32 + q * 8];
            fb[1][t] = *(const short8*)&sB[1][bn_ * 32 + q * 8];
        }
#pragma unroll
        for (int i = 0; i < 4; ++i)
#pragma unroll
            for (int j = 0; j < 4; ++j) {
                acc[i][j] = __builtin_amdgcn_mfma_f32_16x16x32_bf16(
                    fa[0][i], fb[0][j], acc[i][j], 0, 0, 0);
                acc[i][j] = __builtin_amdgcn_mfma_f32_16x16x32_bf16(
                    fa[0][i], fb[1][j], acc[i][j], 0, 0, 0);
                acc[i][j] = __builtin_amdgcn_mfma_f32_16x16x32_bf16(
                    fa[1][i], fb[0][j], acc[i][j], 0, 0, 0);
            }
    }

#pragma unroll
    for (int i = 0; i < 4; ++i)
#pragma unroll
        for (int j = 0; j < 4; ++j)
#pragma unroll
            for (int g = 0; g < 4; ++g) {
                int row = bm * 128 + wm * 64 + i * 16 + q * 4 + g;
                int col = bn * 128 + wn * 64 + j * 16 + r;
                float v = acc[i][j][g];
                size_t off = (size_t)row * KQ + col;
                C[off] = v;
                Ck[off] = (u16)(order_key(v) >> 16);
            }
}

// ---------------------------------------------------------------------------
// fp32 fallback GEMM (only if ws too small for planes) + keygen helper
// ---------------------------------------------------------------------------
#define LSTR 68
#define LA(k, m) ((k) * LSTR + (m))

__global__ __launch_bounds__(256) void gemm_nt_kernel(
    const float* __restrict__ A, const float* __restrict__ B,
    float* __restrict__ C) {
    __shared__ float As[32 * LSTR];
    __shared__ float Bs[32 * LSTR];
    int tid = threadIdx.x;
    int bn = blockIdx.x, bm = blockIdx.y;
    int tx = tid & 15, ty = tid >> 4;
    int lm = tid >> 3;
    int lk = (tid & 7) * 4;
    const float* Ab = A + (size_t)bm * 64 * DIM;
    const float* Bb = B + (size_t)bn * 64 * DIM;
    float acc[4][4] = {};
    for (int kt = 0; kt < DIM; kt += 32) {
        float4 a0 = *(const float4*)(Ab + (size_t)lm * DIM + kt + lk);
        float4 a1 = *(const float4*)(Ab + (size_t)(lm + 32) * DIM + kt + lk);
        float4 b0 = *(const float4*)(Bb + (size_t)lm * DIM + kt + lk);
        float4 b1 = *(const float4*)(Bb + (size_t)(lm + 32) * DIM + kt + lk);
        __syncthreads();
        As[LA(lk + 0, lm)] = a0.x;  As[LA(lk + 1, lm)] = a0.y;
        As[LA(lk + 2, lm)] = a0.z;  As[LA(lk + 3, lm)] = a0.w;
        As[LA(lk + 0, lm + 32)] = a1.x;  As[LA(lk + 1, lm + 32)] = a1.y;
        As[LA(lk + 2, lm + 32)] = a1.z;  As[LA(lk + 3, lm + 32)] = a1.w;
        Bs[LA(lk + 0, lm)] = b0.x;  Bs[LA(lk + 1, lm)] = b0.y;
        Bs[LA(lk + 2, lm)] = b0.z;  Bs[LA(lk + 3, lm)] = b0.w;
        Bs[LA(lk + 0, lm + 32)] = b1.x;  Bs[LA(lk + 1, lm + 32)] = b1.y;
        Bs[LA(lk + 2, lm + 32)] = b1.z;  Bs[LA(lk + 3, lm + 32)] = b1.w;
        __syncthreads();
#pragma unroll
        for (int kk = 0; kk < 32; ++kk) {
            float4 av = *(const float4*)&As[LA(kk, ty * 4)];
            float4 bv = *(const float4*)&Bs[LA(kk, tx * 4)];
            float a_[4] = {av.x, av.y, av.z, av.w};
            float b_[4] = {bv.x, bv.y, bv.z, bv.w};
#pragma unroll
            for (int i = 0; i < 4; ++i)
#pragma unroll
                for (int j = 0; j < 4; ++j) acc[i][j] += a_[i] * b_[j];
        }
    }
    for (int i = 0; i < 4; ++i) {
        float4 o = make_float4(acc[i][0], acc[i][1], acc[i][2], acc[i][3]);
        *(float4*)(C + (size_t)(bm * 64 + ty * 4 + i) * KQ + bn * 64 + tx * 4) = o;
    }
}

__global__ __launch_bounds__(256) void keygen_kernel(
    const float* __restrict__ sim, u16* __restrict__ keys) {
    size_t i = ((size_t)blockIdx.x * 256 + threadIdx.x) * 4;
    float4 v = *(const float4*)(sim + i);
    U16x4 k;
    k.x = (u16)(order_key(v.x) >> 16);
    k.y = (u16)(order_key(v.y) >> 16);
    k.z = (u16)(order_key(v.z) >> 16);
    k.w = (u16)(order_key(v.w) >> 16);
    *(U16x4*)(keys + i) = k;
}

// ---------------------------------------------------------------------------
// Per-row top-200 v3: stream u16 keys (half the bytes), histogram + threshold,
// collect candidate indices, gather exact f32 values, exact rank + vote.
// Bit-identical result to the f32 2-pass version: bins = key16>>4 = okey>>20,
// candidate set identical, rank/vote on gathered exact f32.
// ---------------------------------------------------------------------------
__global__ __launch_bounds__(1024) void topk_kernel(
    const float* __restrict__ sim, const u16* __restrict__ keys, int r0,
    const int* __restrict__ ql, const int* __restrict__ labels,
    float* __restrict__ flags) {
    __shared__ unsigned hist[NBINS];
    __shared__ float cval[CAP];
    __shared__ int   cidx[CAP];
    __shared__ float scores[NCLS];
    __shared__ unsigned wsum[16];
    __shared__ float rb[16];
    __shared__ int   rc[16];
    __shared__ int s_bstar, s_ncand;

    int row = blockIdx.x;
    int tid = threadIdx.x;
    int lane = tid & 63;
    int wv = tid >> 6;
    const uint4* k8 = (const uint4*)(keys + (size_t)row * KQ);   // 8 keys/load
    const float* srow = sim + (size_t)row * KQ;

    hist[tid] = 0; hist[tid + 1024] = 0; hist[tid + 2048] = 0; hist[tid + 3072] = 0;
    if (tid == 0) s_ncand = 0;
    __syncthreads();

    // pass 1: histogram from packed keys (8 per 16B load, 8 iters/thread)
    for (int i8 = tid; i8 < KQ / 8; i8 += 1024) {
        uint4 w = k8[i8];
        atomicAdd(&hist[(w.x >> 4) & 0xFFFu], 1u);
        atomicAdd(&hist[ w.x >> 20          ], 1u);
        atomicAdd(&hist[(w.y >> 4) & 0xFFFu], 1u);
        atomicAdd(&hist[ w.y >> 20          ], 1u);
        atomicAdd(&hist[(w.z >> 4) & 0xFFFu], 1u);
        atomicAdd(&hist[ w.z >> 20          ], 1u);
        atomicAdd(&hist[(w.w >> 4) & 0xFFFu], 1u);
        atomicAdd(&hist[ w.w >> 20          ], 1u);
    }
    __syncthreads();

    // suffix scan: thread t owns bins [4t, 4t+4). Wave shfl suffix + cross-wave.
    unsigned loc = hist[4 * tid] + hist[4 * tid + 1] +
                   hist[4 * tid + 2] + hist[4 * tid + 3];
    unsigned x = loc;
#pragma unroll
    for (int off = 1; off < 64; off <<= 1) {
        unsigned y = __shfl_down(x, off);
        if (lane + off < 64) x += y;
    }
    if (lane == 0) wsum[wv] = x;
    __syncthreads();
    unsigned above = 0;
#pragma unroll
    for (int w2 = 0; w2 < 16; ++w2)
        if (w2 > wv) above += wsum[w2];
    unsigned running = above + x - loc;   // count in bins above this thread's chunk
    for (int j = 3; j >= 0; --j) {
        unsigned c = hist[4 * tid + j];
        if (running < KNN && running + c >= KNN) s_bstar = 4 * tid + j;
        running += c;
    }
    __syncthreads();
    int bstar = s_bstar;

    // pass 2: collect candidate INDICES with bin >= b*
    for (int i8 = tid; i8 < KQ / 8; i8 += 1024) {
        uint4 w = k8[i8];
        int base = i8 * 8;
        unsigned words[4] = {w.x, w.y, w.z, w.w};
#pragma unroll
        for (int t = 0; t < 4; ++t) {
            if ((int)((words[t] >> 4) & 0xFFFu) >= bstar) {
                int p = atomicAdd(&s_ncand, 1);
                if (p < CAP) cidx[p] = base + 2 * t;
            }
            if ((int)(words[t] >> 20) >= bstar) {
                int p = atomicAdd(&s_ncand, 1);
                if (p < CAP) cidx[p] = base + 2 * t + 1;
            }
        }
    }
    if (tid < NCLS) scores[tid] = 0.f;
    __syncthreads();

    // gather exact f32 values for candidates
    int M = s_ncand; if (M > CAP) M = CAP;
    for (int c = tid; c < M; c += 1024) cval[c] = srow[cidx[c]];
    __syncthreads();

    // exact rank among candidates; vote
    for (int c = tid; c < M; c += 1024) {
        float v = cval[c]; int id = cidx[c];
        int rank = 0;
        for (int j = 0; j < M; ++j) {
            float vj = cval[j];
            if (vj > v || (vj == v && cidx[j] < id)) rank++;
        }
        if (rank < KNN) {
            float w = expf(v * INV_T);
            atomicAdd(&scores[ql[id]], w);
        }
    }
    __syncthreads();

    // argmax over classes (ties -> lowest class) via wave shuffles
    float b2 = (tid < NCLS) ? scores[tid] : -1.f;
    int   c2 = (tid < NCLS) ? tid : 0x3FFFFFFF;
#pragma unroll
    for (int off = 1; off < 64; off <<= 1) {
        float ob = __shfl_down(b2, off);
        int   oc = __shfl_down(c2, off);
        if (lane + off < 64 && (ob > b2 || (ob == b2 && oc < c2))) { b2 = ob; c2 = oc; }
    }
    if (lane == 0) { rb[wv] = b2; rc[wv] = c2; }
    __syncthreads();
    if (tid < 64) {
        float b3 = -1.f; int c3 = 0x3FFFFFFF;
        if (tid < 16) { b3 = rb[tid]; c3 = rc[tid]; }
#pragma unroll
        for (int off = 1; off < 16; off <<= 1) {
            float ob = __shfl_down(b3, off);
            int   oc = __shfl_down(c3, off);
            if (tid + off < 16 && (ob > b3 || (ob == b3 && oc < c3))) { b3 = ob; c3 = oc; }
        }
        if (tid == 0)
            flags[r0 + row] = (c3 == labels[r0 + row]) ? 1.0f : 0.0f;
    }
}

__global__ __launch_bounds__(256) void acc_kernel(
    const float* __restrict__ flags, float* __restrict__ out) {
    __shared__ float r[256];
    int tid = threadIdx.x;
    r[tid] = flags[tid] + flags[tid + 256] + flags[tid + 512] + flags[tid + 768];
    __syncthreads();
    for (int off = 128; off; off >>= 1) {
        if (tid < off) r[tid] += r[tid + off];
        __syncthreads();
    }
    if (tid == 0) out[0] = r[0] * (1.0f / 1024.0f);
}

// ---------------------------------------------------------------------------
extern "C" void kernel_launch(void* const* d_in, const int* in_sizes, int n_in,
                              void* d_out, int out_size, void* d_ws, size_t ws_size,
                              hipStream_t stream) {
    const float* feats  = (const float*)d_in[0];
    const float* qf     = (const float*)d_in[1];
    const int*   labels = (const int*)d_in[2];
    const int*   ql     = (const int*)d_in[3];
    const int*   qptr   = (const int*)d_in[4];

    float* out     = (float*)d_out;
    float* out_qf  = out + 1;
    float* out_ql  = out_qf + (size_t)KQ * DIM;
    float* out_ptr = out_ql + KQ;

    const size_t bplane = (size_t)KQ * DIM;
    const size_t aplane = (size_t)N_ROWS * DIM;

    int CH = 0;
    for (int c = 512; c >= 128; c >>= 1) {
        size_t need = 2 * bplane * 2 + 2 * aplane * 2 +
                      (size_t)c * KQ * 4 + (size_t)c * KQ * 2 + N_ROWS * 4;
        if (need <= ws_size) { CH = c; break; }
    }

    if (CH > 0) {
        u16* Bhi = (u16*)d_ws;
        u16* Blo = Bhi + bplane;
        u16* Ahi = Blo + bplane;
        u16* Alo = Ahi + aplane;
        float* sim   = (float*)(Alo + aplane);
        u16*   keys  = (u16*)(sim + (size_t)CH * KQ);
        float* flags = (float*)(keys + (size_t)CH * KQ);

        fused_update_split_kernel<<<QF_BLOCKS + FT_BLOCKS, 256, 0, stream>>>(
            feats, qf, labels, ql, qptr, out_qf, out_ql, out_ptr,
            Bhi, Blo, Ahi, Alo);

        int nchunks = N_ROWS / CH;
        for (int c = 0; c < nchunks; ++c) {
            if (CH >= 256) {
                dim3 g(KQ / 256, CH / 256);
                gemm256_kernel<<<g, 512, 0, stream>>>(
                    Ahi + (size_t)c * CH * DIM, Alo + (size_t)c * CH * DIM,
                    Bhi, Blo, sim, keys);
            } else {
                dim3 g(KQ / 128, CH / 128);
                gemm_mfma_kernel<<<g, 256, 0, stream>>>(
                    Ahi + (size_t)c * CH * DIM, Alo + (size_t)c * CH * DIM,
                    Bhi, Blo, sim, keys);
            }
            topk_kernel<<<CH, 1024, 0, stream>>>(sim, keys, c * CH, ql, labels, flags);
        }
        acc_kernel<<<1, 256, 0, stream>>>(flags, out);
    } else {
        // fp32 fallback path
        int CHf = 256;
        while (CHf > 64 &&
               ((size_t)CHf * KQ * 6 + N_ROWS * sizeof(float)) > ws_size)
            CHf >>= 1;
        float* sim   = (float*)d_ws;
        u16*   keys  = (u16*)(sim + (size_t)CHf * KQ);
        float* flags = (float*)(keys + (size_t)CHf * KQ);
        fused_update_split_kernel<<<QF_BLOCKS + FT_BLOCKS, 256, 0, stream>>>(
            feats, qf, labels, ql, qptr, out_qf, out_ql, out_ptr,
            (u16*)sim, (u16*)sim, (u16*)sim, (u16*)sim);
        int nchunks = N_ROWS / CHf;
        for (int c = 0; c < nchunks; ++c) {
            const float* A = feats + (size_t)c * CHf * DIM;
            dim3 g(KQ / 64, CHf / 64);
            gemm_nt_kernel<<<g, 256, 0, stream>>>(A, qf, sim);
            keygen_kernel<<<(int)((size_t)CHf * KQ / 4 / 256), 256, 0, stream>>>(
                sim, keys);
            topk_kernel<<<CHf, 1024, 0, stream>>>(sim, keys, c * CHf, ql, labels, flags);
        }
        acc_kernel<<<1, 256, 0, stream>>>(flags, out);
    }
}